// Round 2
// baseline (1244.671 us; speedup 1.0000x reference)
//
#include <hip/hip_runtime.h>
#include <hip/hip_bf16.h>

#define N_NODES 100000
#define N_EDGES 640000
#define D_XX 128
#define D_EE 32
#define D_O  128

// ---------- helpers ----------
__device__ __forceinline__ float4 fma4(float4 a, float s, float4 b) {
    a.x = fmaf(s, b.x, a.x);
    a.y = fmaf(s, b.y, a.y);
    a.z = fmaf(s, b.z, a.z);
    a.w = fmaf(s, b.w, a.w);
    return a;
}

// ---------- K0: fold weights ----------
// A[i][j] = sum_k Wx[i][k] * Wm[k][j]                (i,j in [0,128))
// B[i][j] = sum_k We[i][k] * Wm[128+k][j]            (i in [0,32))
// c[j]    = bm[j] + sum_k bx[k]*Wm[k][j] + sum_k be[k]*Wm[128+k][j]
__global__ __launch_bounds__(256) void k_fold(
    const float* __restrict__ Wx, const float* __restrict__ bx,
    const float* __restrict__ We, const float* __restrict__ be,
    const float* __restrict__ Wm, const float* __restrict__ bm,
    float* __restrict__ A, float* __restrict__ B, float* __restrict__ c) {
    int idx = blockIdx.x * 256 + threadIdx.x;
    if (idx < 16384) {
        int i = idx >> 7, j = idx & 127;
        float s = 0.f;
        for (int k = 0; k < 128; ++k) s = fmaf(Wx[i * 128 + k], Wm[k * 128 + j], s);
        A[idx] = s;
    } else if (idx < 16384 + 4096) {
        int t = idx - 16384;
        int i = t >> 7, j = t & 127;
        float s = 0.f;
        for (int k = 0; k < 128; ++k) s = fmaf(We[i * 128 + k], Wm[(128 + k) * 128 + j], s);
        B[t] = s;
    } else if (idx < 16384 + 4096 + 128) {
        int j = idx - 20480;
        float s = bm[j];
        for (int k = 0; k < 128; ++k) s = fmaf(bx[k], Wm[k * 128 + j], s);
        for (int k = 0; k < 128; ++k) s = fmaf(be[k], Wm[(128 + k) * 128 + j], s);
        c[j] = s;
    }
}

// ---------- K_detect: is edge_index int32 or int64? ----------
// int64 little-endian with values < 2^31 => every odd int32 word is 0.
// int32 => odd words are random node ids, OR over 32 of them != 0 w.p. ~1.
__global__ void k_detect(const int* __restrict__ ei, int* __restrict__ flag) {
    if (threadIdx.x == 0 && blockIdx.x == 0) {
        int o = 0;
        for (int i = 1; i < 64; i += 2) o |= ei[i];
        flag[0] = (o != 0) ? 1 : 0;  // 1 => int32, 0 => int64
    }
}

// ---------- K_zero ----------
__global__ __launch_bounds__(256) void k_zero(float4* __restrict__ p, int n4) {
    int i = blockIdx.x * 256 + threadIdx.x;
    int stride = gridDim.x * 256;
    float4 z = make_float4(0.f, 0.f, 0.f, 0.f);
    for (; i < n4; i += stride) p[i] = z;
}

// ---------- K1: n2 = x @ A + c   [100000,128] ----------
// block: 256 thr = 32 j-threads (4 cols each) x 8 node-groups (2 nodes each)
// => 16 nodes/block. x tile in LDS (8KB); A (64KB) read from global —
// wave-uniform addresses per k-step => L1 broadcast, no LDS pressure.
__global__ __launch_bounds__(256) void k_node(
    const float* __restrict__ x, const float* __restrict__ A,
    const float* __restrict__ c, float* __restrict__ n2) {
    __shared__ float xs[16 * 128];
    int tid = threadIdx.x;
    int nb = blockIdx.x * 16;
    {
        const float4* xg = (const float4*)(x + (size_t)nb * 128);
        float4* xs4 = (float4*)xs;
        for (int i = tid; i < 512; i += 256) xs4[i] = xg[i];
    }
    __syncthreads();
    int tj = tid & 31, tn = tid >> 5;
    int j0 = tj * 4;
    float4 cc = *(const float4*)(c + j0);
    float4 acc0 = cc, acc1 = cc;
    const float* xr0 = xs + tn * 128;
    const float* xr1 = xs + (tn + 8) * 128;
    const float* Ap = A + j0;
#pragma unroll 4
    for (int k = 0; k < 128; k += 4) {
        float4 a0 = *(const float4*)(Ap + (size_t)(k + 0) * 128);
        float4 a1 = *(const float4*)(Ap + (size_t)(k + 1) * 128);
        float4 a2 = *(const float4*)(Ap + (size_t)(k + 2) * 128);
        float4 a3 = *(const float4*)(Ap + (size_t)(k + 3) * 128);
        float4 xa = *(const float4*)(xr0 + k);
        float4 xb = *(const float4*)(xr1 + k);
        acc0 = fma4(acc0, xa.x, a0); acc1 = fma4(acc1, xb.x, a0);
        acc0 = fma4(acc0, xa.y, a1); acc1 = fma4(acc1, xb.y, a1);
        acc0 = fma4(acc0, xa.z, a2); acc1 = fma4(acc1, xb.z, a2);
        acc0 = fma4(acc0, xa.w, a3); acc1 = fma4(acc1, xb.w, a3);
    }
    *(float4*)(n2 + (size_t)(nb + tn) * 128 + j0) = acc0;
    *(float4*)(n2 + (size_t)(nb + tn + 8) * 128 + j0) = acc1;
}

// ---------- K2: per-edge  s = n2[src] + ea@B ; leaky ; agg[dst] += s ----------
// block: 256 thr = 32 j-threads x 8 edge-groups; 16 edges per chunk (2 per group)
__global__ __launch_bounds__(256) void k_edge(
    const float* __restrict__ ea, const void* __restrict__ ei_raw,
    const float* __restrict__ B, const float* __restrict__ n2,
    float* __restrict__ agg, const int* __restrict__ flag) {
    __shared__ float Bs[32 * 128];
    int tid = threadIdx.x;
    {
        const float4* Bg = (const float4*)B;
        float4* Bs4 = (float4*)Bs;
        for (int i = tid; i < 1024; i += 256) Bs4[i] = Bg[i];
    }
    __syncthreads();
    const int is32 = flag[0];
    const int* ei32 = (const int*)ei_raw;
    const long long* ei64 = (const long long*)ei_raw;
    int tj = tid & 31, g = tid >> 5;
    int j0 = tj * 4;
    for (int chunk = blockIdx.x; chunk < N_EDGES / 16; chunk += gridDim.x) {
#pragma unroll
        for (int ep = 0; ep < 2; ++ep) {
            int e = chunk * 16 + ep * 8 + g;
            int src, dst;
            if (is32) {
                src = ei32[e];
                dst = ei32[N_EDGES + e];
            } else {
                src = (int)ei64[e];
                dst = (int)ei64[N_EDGES + e];
            }
            const float4* eav = (const float4*)(ea + (size_t)e * 32);
            float4 acc = *(const float4*)(n2 + (size_t)src * 128 + j0);
#pragma unroll
            for (int k8 = 0; k8 < 8; ++k8) {
                float4 e4 = eav[k8];
                const float* Bb = Bs + k8 * 4 * 128 + j0;
                acc = fma4(acc, e4.x, *(const float4*)(Bb));
                acc = fma4(acc, e4.y, *(const float4*)(Bb + 128));
                acc = fma4(acc, e4.z, *(const float4*)(Bb + 256));
                acc = fma4(acc, e4.w, *(const float4*)(Bb + 384));
            }
            // leaky_relu, slope 0.01
            acc.x = acc.x > 0.f ? acc.x : 0.01f * acc.x;
            acc.y = acc.y > 0.f ? acc.y : 0.01f * acc.y;
            acc.z = acc.z > 0.f ? acc.z : 0.01f * acc.z;
            acc.w = acc.w > 0.f ? acc.w : 0.01f * acc.w;
            float* ap = agg + (size_t)dst * 128 + j0;
            unsafeAtomicAdd(ap + 0, acc.x);
            unsafeAtomicAdd(ap + 1, acc.y);
            unsafeAtomicAdd(ap + 2, acc.z);
            unsafeAtomicAdd(ap + 3, acc.w);
        }
    }
}

// ---------- K3: out = f32( sigmoid(agg) * relu(beta) ) ----------
__global__ __launch_bounds__(256) void k_final(
    const float* __restrict__ agg, const float* __restrict__ beta,
    float4* __restrict__ out) {
    float rb = fmaxf(beta[0], 0.f);
    int i = blockIdx.x * 256 + threadIdx.x;
    int stride = gridDim.x * 256;
    const float4* a4 = (const float4*)agg;
    const int n4 = N_NODES * D_O / 4;
    for (; i < n4; i += stride) {
        float4 v = a4[i];
        float4 r;
        r.x = rb / (1.f + __expf(-v.x));
        r.y = rb / (1.f + __expf(-v.y));
        r.z = rb / (1.f + __expf(-v.z));
        r.w = rb / (1.f + __expf(-v.w));
        out[i] = r;
    }
}

// ---------- launch ----------
extern "C" void kernel_launch(void* const* d_in, const int* in_sizes, int n_in,
                              void* d_out, int out_size, void* d_ws, size_t ws_size,
                              hipStream_t stream) {
    const float* x    = (const float*)d_in[0];
    const float* ea   = (const float*)d_in[1];
    const float* Wx   = (const float*)d_in[2];
    const float* bx   = (const float*)d_in[3];
    const float* We   = (const float*)d_in[4];
    const float* be   = (const float*)d_in[5];
    const float* Wm   = (const float*)d_in[6];
    const float* bm   = (const float*)d_in[7];
    const float* beta = (const float*)d_in[8];
    const void*  ei   = d_in[9];

    // workspace layout (bytes):
    //   A @0 (65536), B @65536 (16384), c @81920 (512), flag @82432 (4)
    //   n2 @131072 (51200000), agg @51331072 (51200000) -> end 102531072
    if (ws_size < (size_t)102531072) return;  // breadcrumb: leaves d_out zeroed

    char* ws = (char*)d_ws;
    float* A    = (float*)ws;
    float* B    = (float*)(ws + 65536);
    float* c    = (float*)(ws + 81920);
    int*   flag = (int*)(ws + 82432);
    float* n2   = (float*)(ws + 131072);
    float* agg  = (float*)(ws + 131072 + 51200000);

    k_fold<<<81, 256, 0, stream>>>(Wx, bx, We, be, Wm, bm, A, B, c);
    k_detect<<<1, 64, 0, stream>>>((const int*)ei, flag);
    k_zero<<<2048, 256, 0, stream>>>((float4*)agg, N_NODES * D_O / 4);
    k_node<<<N_NODES / 16, 256, 0, stream>>>(x, A, c, n2);
    k_edge<<<4096, 256, 0, stream>>>(ea, ei, B, n2, agg, flag);
    k_final<<<2048, 256, 0, stream>>>(agg, beta, (float4*)d_out);
}

// Round 3
// 464.030 us; speedup vs baseline: 2.6823x; 2.6823x over previous
//
#include <hip/hip_runtime.h>
#include <hip/hip_bf16.h>

#define N_NODES 100000
#define N_EDGES 640000
#define D_EE 32
#define D_O  128
#define SCAN_CHUNK 1024
#define NB_SCAN ((N_NODES + SCAN_CHUNK - 1) / SCAN_CHUNK)  // 98

// ---------- helpers ----------
__device__ __forceinline__ float4 fma4(float4 a, float s, float4 b) {
    a.x = fmaf(s, b.x, a.x);
    a.y = fmaf(s, b.y, a.y);
    a.z = fmaf(s, b.z, a.z);
    a.w = fmaf(s, b.w, a.w);
    return a;
}

// ---------- K0: fold weights ----------
// A[i][j] = sum_k Wx[i][k]*Wm[k][j];  B[i][j] = sum_k We[i][k]*Wm[128+k][j]
// c[j] = bm[j] + sum_k bx[k]*Wm[k][j] + sum_k be[k]*Wm[128+k][j]
__global__ __launch_bounds__(256) void k_fold(
    const float* __restrict__ Wx, const float* __restrict__ bx,
    const float* __restrict__ We, const float* __restrict__ be,
    const float* __restrict__ Wm, const float* __restrict__ bm,
    float* __restrict__ A, float* __restrict__ B, float* __restrict__ c) {
    int idx = blockIdx.x * 256 + threadIdx.x;
    if (idx < 16384) {
        int i = idx >> 7, j = idx & 127;
        float s = 0.f;
        for (int k = 0; k < 128; ++k) s = fmaf(Wx[i * 128 + k], Wm[k * 128 + j], s);
        A[idx] = s;
    } else if (idx < 16384 + 4096) {
        int t = idx - 16384;
        int i = t >> 7, j = t & 127;
        float s = 0.f;
        for (int k = 0; k < 128; ++k) s = fmaf(We[i * 128 + k], Wm[(128 + k) * 128 + j], s);
        B[t] = s;
    } else if (idx < 16384 + 4096 + 128) {
        int j = idx - 20480;
        float s = bm[j];
        for (int k = 0; k < 128; ++k) s = fmaf(bx[k], Wm[k * 128 + j], s);
        for (int k = 0; k < 128; ++k) s = fmaf(be[k], Wm[(128 + k) * 128 + j], s);
        c[j] = s;
    }
}

// ---------- detect int32 vs int64 edge_index ----------
__global__ void k_detect(const int* __restrict__ ei, int* __restrict__ flag) {
    if (threadIdx.x == 0 && blockIdx.x == 0) {
        int o = 0;
        for (int i = 1; i < 64; i += 2) o |= ei[i];
        flag[0] = (o != 0) ? 1 : 0;  // 1 => int32, 0 => int64
    }
}

// ---------- zero ints (float4-wide) ----------
__global__ __launch_bounds__(256) void k_zero(float4* __restrict__ p, int n4) {
    int i = blockIdx.x * 256 + threadIdx.x;
    int stride = gridDim.x * 256;
    float4 z = make_float4(0.f, 0.f, 0.f, 0.f);
    for (; i < n4; i += stride) p[i] = z;
}

// ---------- extract indices to int32 + histogram of dst ----------
__global__ __launch_bounds__(256) void k_extract_hist(
    const void* __restrict__ ei_raw, const int* __restrict__ flag,
    int* __restrict__ srcA, int* __restrict__ dstA, int* __restrict__ counts) {
    int e = blockIdx.x * 256 + threadIdx.x;
    if (e >= N_EDGES) return;
    int src, dst;
    if (flag[0]) {
        const int* ei32 = (const int*)ei_raw;
        src = ei32[e];
        dst = ei32[N_EDGES + e];
    } else {
        const long long* ei64 = (const long long*)ei_raw;
        src = (int)ei64[e];
        dst = (int)ei64[N_EDGES + e];
    }
    srcA[e] = src;
    dstA[e] = dst;
    atomicAdd(&counts[dst], 1);
}

// ---------- scan A: per-1024-chunk sums ----------
__global__ __launch_bounds__(256) void k_scan_a(
    const int* __restrict__ counts, int* __restrict__ bsum) {
    __shared__ int L[256];
    int b = blockIdx.x, t = threadIdx.x;
    int base = b * SCAN_CHUNK + t * 4;
    int s = 0;
#pragma unroll
    for (int r = 0; r < 4; ++r) {
        int i = base + r;
        if (i < N_NODES) s += counts[i];
    }
    L[t] = s;
    __syncthreads();
    for (int h = 128; h > 0; h >>= 1) {
        if (t < h) L[t] += L[t + h];
        __syncthreads();
    }
    if (t == 0) bsum[b] = L[0];
}

// ---------- scan B: exclusive scan of block sums (serial, tiny) ----------
__global__ void k_scan_b(const int* __restrict__ bsum, int* __restrict__ boff) {
    if (threadIdx.x == 0 && blockIdx.x == 0) {
        int run = 0;
        for (int i = 0; i < NB_SCAN; ++i) { boff[i] = run; run += bsum[i]; }
    }
}

// ---------- scan C: final exclusive offsets ----------
__global__ __launch_bounds__(256) void k_scan_c(
    const int* __restrict__ counts, const int* __restrict__ boff,
    int* __restrict__ offsets) {
    __shared__ int L[256];
    int b = blockIdx.x, t = threadIdx.x;
    int base = b * SCAN_CHUNK + t * 4;
    int c0 = 0, c1 = 0, c2 = 0, c3 = 0;
    if (base + 0 < N_NODES) c0 = counts[base + 0];
    if (base + 1 < N_NODES) c1 = counts[base + 1];
    if (base + 2 < N_NODES) c2 = counts[base + 2];
    if (base + 3 < N_NODES) c3 = counts[base + 3];
    L[t] = c0 + c1 + c2 + c3;
    __syncthreads();
    if (t == 0) {
        int run = 0;
        for (int i = 0; i < 256; ++i) { int tmp = L[i]; L[i] = run; run += tmp; }
    }
    __syncthreads();
    int o = boff[b] + L[t];
    if (base + 0 < N_NODES) offsets[base + 0] = o;
    if (base + 1 < N_NODES) offsets[base + 1] = o + c0;
    if (base + 2 < N_NODES) offsets[base + 2] = o + c0 + c1;
    if (base + 3 < N_NODES) offsets[base + 3] = o + c0 + c1 + c2;
}

// ---------- scatter: perm by dst ----------
__global__ __launch_bounds__(256) void k_scatter(
    const int* __restrict__ dstA, const int* __restrict__ offsets,
    int* __restrict__ cursor, int* __restrict__ perm) {
    int e = blockIdx.x * 256 + threadIdx.x;
    if (e >= N_EDGES) return;
    int d = dstA[e];
    int pos = offsets[d] + atomicAdd(&cursor[d], 1);
    perm[pos] = e;
}

// ---------- K1: n2 = x @ A + c   [100000,128] ----------
__global__ __launch_bounds__(256) void k_node(
    const float* __restrict__ x, const float* __restrict__ A,
    const float* __restrict__ c, float* __restrict__ n2) {
    __shared__ float xs[16 * 128];
    int tid = threadIdx.x;
    int nb = blockIdx.x * 16;
    {
        const float4* xg = (const float4*)(x + (size_t)nb * 128);
        float4* xs4 = (float4*)xs;
        for (int i = tid; i < 512; i += 256) xs4[i] = xg[i];
    }
    __syncthreads();
    int tj = tid & 31, tn = tid >> 5;
    int j0 = tj * 4;
    float4 cc = *(const float4*)(c + j0);
    float4 acc0 = cc, acc1 = cc;
    const float* xr0 = xs + tn * 128;
    const float* xr1 = xs + (tn + 8) * 128;
    const float* Ap = A + j0;
#pragma unroll 4
    for (int k = 0; k < 128; k += 4) {
        float4 a0 = *(const float4*)(Ap + (size_t)(k + 0) * 128);
        float4 a1 = *(const float4*)(Ap + (size_t)(k + 1) * 128);
        float4 a2 = *(const float4*)(Ap + (size_t)(k + 2) * 128);
        float4 a3 = *(const float4*)(Ap + (size_t)(k + 3) * 128);
        float4 xa = *(const float4*)(xr0 + k);
        float4 xb = *(const float4*)(xr1 + k);
        acc0 = fma4(acc0, xa.x, a0); acc1 = fma4(acc1, xb.x, a0);
        acc0 = fma4(acc0, xa.y, a1); acc1 = fma4(acc1, xb.y, a1);
        acc0 = fma4(acc0, xa.z, a2); acc1 = fma4(acc1, xb.z, a2);
        acc0 = fma4(acc0, xa.w, a3); acc1 = fma4(acc1, xb.w, a3);
    }
    *(float4*)(n2 + (size_t)(nb + tn) * 128 + j0) = acc0;
    *(float4*)(n2 + (size_t)(nb + tn + 8) * 128 + j0) = acc1;
}

// ---------- K2: gather per dst node, fused epilogue ----------
// one wave per node; lane owns output cols {lane, lane+64}.
// B columns preloaded into 64 VGPRs; per edge: uniform-broadcast ea loads,
// coalesced n2[src] gather; accumulate leaky(msg); write sigmoid*rb once.
__global__ __launch_bounds__(256) void k_gather(
    const float* __restrict__ n2, const float* __restrict__ ea,
    const int* __restrict__ srcA, const int* __restrict__ perm,
    const int* __restrict__ offsets, const int* __restrict__ counts,
    const float* __restrict__ B, const float* __restrict__ beta,
    float* __restrict__ out) {
    int lane = threadIdx.x & 63;
    int wid = (blockIdx.x * 256 + threadIdx.x) >> 6;
    int nw = gridDim.x * 4;
    float rb = fmaxf(beta[0], 0.f);
    float b0[32], b1[32];
#pragma unroll
    for (int k = 0; k < 32; ++k) {
        b0[k] = B[k * 128 + lane];
        b1[k] = B[k * 128 + 64 + lane];
    }
    for (int node = wid; node < N_NODES; node += nw) {
        int off = offsets[node];
        int cnt = counts[node];
        float acc0 = 0.f, acc1 = 0.f;
        for (int i = 0; i < cnt; ++i) {
            int e = perm[off + i];
            int s = srcA[e];
            const float4* E4 = (const float4*)(ea + (size_t)e * 32);
            float4 E[8];
#pragma unroll
            for (int r = 0; r < 8; ++r) E[r] = E4[r];
            const float* nrow = n2 + (size_t)s * 128;
            float m0 = nrow[lane];
            float m1 = nrow[64 + lane];
#pragma unroll
            for (int r = 0; r < 8; ++r) {
                m0 = fmaf(E[r].x, b0[4 * r + 0], m0);
                m0 = fmaf(E[r].y, b0[4 * r + 1], m0);
                m0 = fmaf(E[r].z, b0[4 * r + 2], m0);
                m0 = fmaf(E[r].w, b0[4 * r + 3], m0);
                m1 = fmaf(E[r].x, b1[4 * r + 0], m1);
                m1 = fmaf(E[r].y, b1[4 * r + 1], m1);
                m1 = fmaf(E[r].z, b1[4 * r + 2], m1);
                m1 = fmaf(E[r].w, b1[4 * r + 3], m1);
            }
            acc0 += (m0 > 0.f) ? m0 : 0.01f * m0;
            acc1 += (m1 > 0.f) ? m1 : 0.01f * m1;
        }
        out[(size_t)node * 128 + lane]      = rb / (1.f + __expf(-acc0));
        out[(size_t)node * 128 + 64 + lane] = rb / (1.f + __expf(-acc1));
    }
}

// ---------- launch ----------
extern "C" void kernel_launch(void* const* d_in, const int* in_sizes, int n_in,
                              void* d_out, int out_size, void* d_ws, size_t ws_size,
                              hipStream_t stream) {
    const float* x    = (const float*)d_in[0];
    const float* ea   = (const float*)d_in[1];
    const float* Wx   = (const float*)d_in[2];
    const float* bx   = (const float*)d_in[3];
    const float* We   = (const float*)d_in[4];
    const float* be   = (const float*)d_in[5];
    const float* Wm   = (const float*)d_in[6];
    const float* bm   = (const float*)d_in[7];
    const float* beta = (const float*)d_in[8];
    const void*  ei   = d_in[9];

    // ws layout (byte offsets, all 16B-aligned):
    //   A       @ 0        (65536)
    //   B       @ 65536    (16384)
    //   c       @ 81920    (512)
    //   flag    @ 82432    (16)
    //   srcA    @ 131072   (2,560,000)
    //   dstA    @ 2691072  (2,560,000)
    //   counts  @ 5251072  (400,000)   | zeroed together
    //   cursor  @ 5651072  (400,000)   |
    //   bsum    @ 6051072  (512)
    //   boff    @ 6051584  (512)
    //   offsets @ 6052096  (400,000)
    //   perm    @ 6452096  (2,560,000)
    //   n2      @ 9437184  (51,200,000) -> end 60,637,184
    if (ws_size < (size_t)60637184) return;

    char* ws = (char*)d_ws;
    float* A      = (float*)(ws);
    float* B      = (float*)(ws + 65536);
    float* c      = (float*)(ws + 81920);
    int*   flag   = (int*)(ws + 82432);
    int*   srcA   = (int*)(ws + 131072);
    int*   dstA   = (int*)(ws + 2691072);
    int*   counts = (int*)(ws + 5251072);
    int*   cursor = (int*)(ws + 5651072);
    int*   bsum   = (int*)(ws + 6051072);
    int*   boff   = (int*)(ws + 6051584);
    int*   offs   = (int*)(ws + 6052096);
    int*   perm   = (int*)(ws + 6452096);
    float* n2     = (float*)(ws + 9437184);

    k_fold<<<81, 256, 0, stream>>>(Wx, bx, We, be, Wm, bm, A, B, c);
    k_detect<<<1, 64, 0, stream>>>((const int*)ei, flag);
    // zero counts+cursor (contiguous 800,000 B = 50,000 float4)
    k_zero<<<196, 256, 0, stream>>>((float4*)counts, 50000);
    k_extract_hist<<<2500, 256, 0, stream>>>(ei, flag, srcA, dstA, counts);
    k_scan_a<<<NB_SCAN, 256, 0, stream>>>(counts, bsum);
    k_scan_b<<<1, 64, 0, stream>>>(bsum, boff);
    k_scan_c<<<NB_SCAN, 256, 0, stream>>>(counts, boff, offs);
    k_scatter<<<2500, 256, 0, stream>>>(dstA, offs, cursor, perm);
    k_node<<<N_NODES / 16, 256, 0, stream>>>(x, A, c, n2);
    k_gather<<<2048, 256, 0, stream>>>(n2, ea, srcA, perm, offs, counts, B, beta,
                                       (float*)d_out);
}